// Round 1
// baseline (14.931 us; speedup 1.0000x reference)
//
#include <hip/hip_runtime.h>

#define NCL_EPS 1e-12f

// One wave (64 lanes) per row: compute 1 - cos(x_i, centers[labels_i]).
__global__ __launch_bounds__(256) void ncl_row_kernel(
    const float* __restrict__ x,
    const int* __restrict__ labels,
    const float* __restrict__ centers,
    float* __restrict__ row_out,
    int batch)
{
    const int gid  = blockIdx.x * blockDim.x + threadIdx.x;
    const int row  = gid >> 6;         // wave index = row
    const int lane = threadIdx.x & 63;
    if (row >= batch) return;

    const float2* xr = reinterpret_cast<const float2*>(x + (size_t)row * 128);
    const int lbl = labels[row];
    const float2* cr = reinterpret_cast<const float2*>(centers + (size_t)lbl * 128);

    const float2 xv = xr[lane];   // 2 floats/lane * 64 lanes = 128 = D
    const float2 cv = cr[lane];

    float xx = xv.x * xv.x + xv.y * xv.y;
    float cc = cv.x * cv.x + cv.y * cv.y;
    float xc = xv.x * cv.x + xv.y * cv.y;

    #pragma unroll
    for (int off = 32; off >= 1; off >>= 1) {
        xx += __shfl_xor(xx, off, 64);
        cc += __shfl_xor(cc, off, 64);
        xc += __shfl_xor(xc, off, 64);
    }

    if (lane == 0) {
        const float nx = fmaxf(sqrtf(xx), NCL_EPS);
        const float nc = fmaxf(sqrtf(cc), NCL_EPS);
        row_out[row] = 1.0f - xc / (nx * nc);
    }
}

// Single-block deterministic reduction of the per-row values.
__global__ __launch_bounds__(256) void ncl_reduce_kernel(
    const float* __restrict__ row_vals,
    float* __restrict__ out,
    int n)
{
    __shared__ float sm[4];
    float s = 0.0f;
    for (int i = threadIdx.x; i < n; i += 256) s += row_vals[i];

    #pragma unroll
    for (int off = 32; off >= 1; off >>= 1) s += __shfl_xor(s, off, 64);

    const int wave = threadIdx.x >> 6;
    if ((threadIdx.x & 63) == 0) sm[wave] = s;
    __syncthreads();

    if (threadIdx.x == 0) {
        out[0] = (sm[0] + sm[1] + sm[2] + sm[3]) / (float)n;
    }
}

extern "C" void kernel_launch(void* const* d_in, const int* in_sizes, int n_in,
                              void* d_out, int out_size, void* d_ws, size_t ws_size,
                              hipStream_t stream) {
    const float* x       = (const float*)d_in[0];
    const int*   labels  = (const int*)d_in[1];
    const float* centers = (const float*)d_in[2];
    float* out = (float*)d_out;

    const int batch = in_sizes[1];          // 4096 labels
    float* row_vals = (float*)d_ws;         // batch floats of scratch

    // 4 rows (waves) per 256-thread block.
    const int blocks = (batch + 3) / 4;
    ncl_row_kernel<<<blocks, 256, 0, stream>>>(x, labels, centers, row_vals, batch);
    ncl_reduce_kernel<<<1, 256, 0, stream>>>(row_vals, out, batch);
}